// Round 8
// baseline (97.533 us; speedup 1.0000x reference)
//
#include <hip/hip_runtime.h>
#include <hip/hip_bf16.h>

typedef __attribute__((ext_vector_type(4))) float f32x4;
typedef __attribute__((ext_vector_type(8))) short bf16x8;

constexpr int B = 4, C = 64, N = 4096;
constexpr int KVSPLIT = 8;
constexpr int CHUNK = N / KVSPLIT;   // 512
constexpr int NQW = B * N / 32;      // 512 q-waves (32 rows each)

__device__ __forceinline__ float bf2f(ushort u) {
    union { float f; unsigned int u32; } x;
    x.u32 = ((unsigned int)u) << 16;
    return x.f;
}
__device__ __forceinline__ ushort f2bf(float f) {
    union { float f; unsigned int u; } x;
    x.f = f;
    unsigned int r = x.u + 0x7FFFu + ((x.u >> 16) & 1u);
    return (ushort)(r >> 16);
}
// guaranteed-order pair: lo 16 = a (even index), hi 16 = b (odd index)
__device__ __forceinline__ uint packbf2(float a, float b) {
    return (uint)f2bf(a) | ((uint)f2bf(b) << 16);
}
__device__ __forceinline__ bf16x8 pack8(uint a, uint b, uint c, uint d) {
    union { uint u[4]; bf16x8 v; } x;
    x.u[0] = a; x.u[1] = b; x.u[2] = c; x.u[3] = d;
    return x.v;
}

#define MFMA16(a, b, c) __builtin_amdgcn_mfma_f32_16x16x32_bf16(a, b, c, 0, 0, 0)

// ---------------------------------------------------------------------------
// Kernel 1: QKV via MFMA (R6-PASSED, unchanged). Zero LDS, zero barriers.
// ---------------------------------------------------------------------------
__global__ __launch_bounds__(256) void qkv_kernel(
    const float* __restrict__ x, const float* __restrict__ Wq,
    const float* __restrict__ Wk, const float* __restrict__ Wv,
    ushort* __restrict__ Q, ushort* __restrict__ K, ushort* __restrict__ Vt)
{
    const int b  = blockIdx.x >> 8;
    const int n0 = (blockIdx.x & 255) << 4;
    const int lane = threadIdx.x & 63;
    const int w  = threadIdx.x >> 6;
    const int lq = lane & 15, lg = lane >> 4;

    bf16x8 bfrag[2];
#pragma unroll
    for (int kk = 0; kk < 2; ++kk) {
        float xv[8];
#pragma unroll
        for (int j = 0; j < 8; ++j)
            xv[j] = x[(size_t)(b * C + kk * 32 + lg * 8 + j) * N + n0 + lq];
        bfrag[kk] = pack8(packbf2(xv[0], xv[1]), packbf2(xv[2], xv[3]),
                          packbf2(xv[4], xv[5]), packbf2(xv[6], xv[7]));
    }

    const float* Ws[3] = {Wq, Wk, Wv};
#pragma unroll
    for (int m = 0; m < 3; ++m) {
        const float scale = (m == 0) ? 0.125f : 1.0f;
        f32x4 acc = {0.f, 0.f, 0.f, 0.f};
#pragma unroll
        for (int kk = 0; kk < 2; ++kk) {
            const float* wp = Ws[m] + (size_t)(w * 16 + lq) * C + kk * 32 + lg * 8;
            const float4 w0 = *(const float4*)wp;
            const float4 w1 = *(const float4*)(wp + 4);
            const bf16x8 af = pack8(
                packbf2(w0.x * scale, w0.y * scale), packbf2(w0.z * scale, w0.w * scale),
                packbf2(w1.x * scale, w1.y * scale), packbf2(w1.z * scale, w1.w * scale));
            acc = MFMA16(af, bfrag[kk], acc);
        }
        if (m < 2) {   // Q/K [b][n][c]
            uint2 u;
            u.x = packbf2(acc[0], acc[1]);
            u.y = packbf2(acc[2], acc[3]);
            ushort* dst = (m == 0 ? Q : K) + ((size_t)(b * N + n0 + lq)) * C + w * 16 + 4 * lg;
            *(uint2*)dst = u;
        } else {       // Vt [b][c][n]
#pragma unroll
            for (int j = 0; j < 4; ++j)
                Vt[(size_t)(b * C + w * 16 + 4 * lg + j) * N + n0 + lq] = f2bf(acc[j]);
        }
    }
}

// ---------------------------------------------------------------------------
// Kernel 2: split-KV attention, BARRIER-FREE. Each wave owns 32 q-rows
// (2 q-tiles) and streams K/V fragments DIRECTLY from global (chunk = 64KB,
// L2-resident per XCD via s=blk&7; frag addressing identical to R1-passed
// kernel). V-frag loads shared by both q-tiles. p_lds is wave-private
// (per-q-tile sub-buffer) -> ordered by lgkmcnt, no __syncthreads at all.
// Epilogue: bf16 pacc + fp32 pl partials (R6-proven), combined in proj.
// ---------------------------------------------------------------------------
__global__ __launch_bounds__(256) void attn_kernel(
    const ushort* __restrict__ Q, const ushort* __restrict__ K,
    const ushort* __restrict__ Vt, ushort* __restrict__ pacc,
    float* __restrict__ pl)
{
    __shared__ ushort p_lds[4][2][16][36] __attribute__((aligned(16)));
    const int tid  = threadIdx.x;
    const int wave = tid >> 6, lane = tid & 63;
    const int lq = lane & 15, lg = lane >> 4;
    const int qg = blockIdx.x >> 3, s = blockIdx.x & 7;   // split <-> XCD
    const int qwg = qg * 4 + wave;          // global q-wave id, 0..511
    const int b   = qwg >> 7;
    const int q0  = (qwg & 127) << 5;       // 32 q-rows per wave

    const ushort* Qb = Q  + ((size_t)b * N + q0) * C;
    const ushort* Kb = K  + ((size_t)b * N + s * CHUNK) * C;
    const ushort* Vb = Vt + (size_t)b * C * N + s * CHUNK;

    bf16x8 qf[2][2];
#pragma unroll
    for (int qi = 0; qi < 2; ++qi) {
        qf[qi][0] = *(const bf16x8*)(Qb + (size_t)(qi * 16 + lq) * C + lg * 8);
        qf[qi][1] = *(const bf16x8*)(Qb + (size_t)(qi * 16 + lq) * C + 32 + lg * 8);
    }

    f32x4 acc[2][4];
#pragma unroll
    for (int qi = 0; qi < 2; ++qi)
#pragma unroll
        for (int nt = 0; nt < 4; ++nt) acc[qi][nt] = (f32x4){0.f, 0.f, 0.f, 0.f};
    float psum[2][4] = {{0.f, 0.f, 0.f, 0.f}, {0.f, 0.f, 0.f, 0.f}};

    constexpr int NT = CHUNK / 32;   // 16 tiles
    for (int t = 0; t < NT; ++t) {
        const int m0 = t * 32;
        // K fragments straight from global (R1-verified addressing)
        const ushort* kp0 = Kb + (size_t)(m0 + lq) * C;
        const ushort* kp1 = Kb + (size_t)(m0 + 16 + lq) * C;
        const bf16x8 k00 = *(const bf16x8*)(kp0 + lg * 8);
        const bf16x8 k01 = *(const bf16x8*)(kp0 + 32 + lg * 8);
        const bf16x8 k10 = *(const bf16x8*)(kp1 + lg * 8);
        const bf16x8 k11 = *(const bf16x8*)(kp1 + 32 + lg * 8);
        // V fragments: shared by both q-tiles
        bf16x8 vf[4];
#pragma unroll
        for (int nt = 0; nt < 4; ++nt)
            vf[nt] = *(const bf16x8*)(Vb + (size_t)(nt * 16 + lq) * N + m0 + lg * 8);

#pragma unroll
        for (int qi = 0; qi < 2; ++qi) {
            f32x4 s0 = (f32x4){0.f, 0.f, 0.f, 0.f};
            f32x4 s1 = (f32x4){0.f, 0.f, 0.f, 0.f};
            s0 = MFMA16(qf[qi][0], k00, s0);
            s0 = MFMA16(qf[qi][1], k01, s0);
            s1 = MFMA16(qf[qi][0], k10, s1);
            s1 = MFMA16(qf[qi][1], k11, s1);

            float p0v[4], p1v[4];
#pragma unroll
            for (int j = 0; j < 4; ++j) {
                p0v[j] = __expf(fminf(s0[j], 30.f));
                p1v[j] = __expf(fminf(s1[j], 30.f));
                psum[qi][j] += p0v[j] + p1v[j];
            }
#pragma unroll
            for (int j = 0; j < 4; ++j) {
                const int row = lg * 4 + j;
                p_lds[wave][qi][row][lq]      = f2bf(p0v[j]);
                p_lds[wave][qi][row][lq + 16] = f2bf(p1v[j]);
            }
            const bf16x8 pa = *(const bf16x8*)&p_lds[wave][qi][lq][lg * 8];
#pragma unroll
            for (int nt = 0; nt < 4; ++nt)
                acc[qi][nt] = MFMA16(pa, vf[nt], acc[qi][nt]);
        }
    }

#pragma unroll
    for (int off = 1; off < 16; off <<= 1) {
#pragma unroll
        for (int qi = 0; qi < 2; ++qi)
#pragma unroll
            for (int j = 0; j < 4; ++j)
                psum[qi][j] += __shfl_xor(psum[qi][j], off);
    }

    // partials: pacc[(qwg*8+s)] = 32x64 bf16 tile; pl rows alongside
    ushort* pb = pacc + ((size_t)qwg * KVSPLIT + s) * (32 * 64);
#pragma unroll
    for (int qi = 0; qi < 2; ++qi)
#pragma unroll
        for (int nt = 0; nt < 4; ++nt)
#pragma unroll
            for (int j = 0; j < 4; ++j)
                pb[(qi * 16 + lg * 4 + j) * 64 + nt * 16 + lq] = f2bf(acc[qi][nt][j]);
    if (lq == 0) {
#pragma unroll
        for (int qi = 0; qi < 2; ++qi)
#pragma unroll
            for (int j = 0; j < 4; ++j)
                pl[((size_t)qwg * KVSPLIT + s) * 32 + qi * 16 + lg * 4 + j] = psum[qi][j];
    }
}

// ---------------------------------------------------------------------------
// Kernel 3: combine 8 splits + projection via MFMA + residual (R6-proven
// structure; split count and pacc layout updated). grid = 512 (32 tok/blk).
// ---------------------------------------------------------------------------
__global__ __launch_bounds__(256) void proj_kernel(
    const float* __restrict__ x, const float* __restrict__ Wp,
    const ushort* __restrict__ pacc, const float* __restrict__ pl,
    float* __restrict__ out)
{
    __shared__ __attribute__((aligned(16))) ushort Hs[32][68];
    __shared__ float linv_s[32];
    const int tid = threadIdx.x;
    const int qw  = blockIdx.x;            // == global q-wave id, 0..511
    const int b   = qw >> 7;
    const int n0  = (qw & 127) << 5;

    if (tid < 32) {
        float sm = 0.f;
#pragma unroll
        for (int s2 = 0; s2 < KVSPLIT; ++s2)
            sm += pl[((size_t)qw * KVSPLIT + s2) * 32 + tid];
        linv_s[tid] = 1.f / sm;
    }
    {   // combine 8 splits: thread -> (tok, 8-channel segment)
        const int tok = tid >> 3, c8 = (tid & 7) * 8;
        const ushort* base = pacc + ((size_t)qw * KVSPLIT) * 2048 + tok * 64 + c8;
        float sm[8] = {0.f, 0.f, 0.f, 0.f, 0.f, 0.f, 0.f, 0.f};
#pragma unroll
        for (int s2 = 0; s2 < KVSPLIT; ++s2) {
            union { bf16x8 v; ushort u[8]; } pk;
            pk.v = *(const bf16x8*)(base + s2 * 2048);
#pragma unroll
            for (int j = 0; j < 8; ++j) sm[j] += bf2f(pk.u[j]);
        }
        *(bf16x8*)&Hs[tok][c8] = pack8(
            packbf2(sm[0], sm[1]), packbf2(sm[2], sm[3]),
            packbf2(sm[4], sm[5]), packbf2(sm[6], sm[7]));
    }
    __syncthreads();

    const int lane = tid & 63, w = tid >> 6;
    const int lq = lane & 15, lg = lane >> 4;

    bf16x8 af[2];
#pragma unroll
    for (int kk = 0; kk < 2; ++kk) {
        const float* wp = Wp + (size_t)(w * 16 + lq) * C + kk * 32 + lg * 8;
        const float4 w0 = *(const float4*)wp;
        const float4 w1 = *(const float4*)(wp + 4);
        af[kk] = pack8(packbf2(w0.x, w0.y), packbf2(w0.z, w0.w),
                       packbf2(w1.x, w1.y), packbf2(w1.z, w1.w));
    }

#pragma unroll
    for (int th = 0; th < 2; ++th) {          // two 16-token D tiles
        f32x4 acc = {0.f, 0.f, 0.f, 0.f};
#pragma unroll
        for (int kk = 0; kk < 2; ++kk) {
            const bf16x8 bf = *(const bf16x8*)&Hs[th * 16 + lq][kk * 32 + lg * 8];
            acc = MFMA16(af[kk], bf, acc);
        }
        const float li = linv_s[th * 16 + lq];
#pragma unroll
        for (int j = 0; j < 4; ++j) {
            const int o = w * 16 + 4 * lg + j;
            const size_t idx = (size_t)(b * C + o) * N + n0 + th * 16 + lq;
            out[idx] = x[idx] + acc[j] * li;
        }
    }
}

// ---------------------------------------------------------------------------
extern "C" void kernel_launch(void* const* d_in, const int* in_sizes, int n_in,
                              void* d_out, int out_size, void* d_ws, size_t ws_size,
                              hipStream_t stream)
{
    const float* x  = (const float*)d_in[0];
    const float* Wq = (const float*)d_in[1];
    const float* Wk = (const float*)d_in[2];
    const float* Wv = (const float*)d_in[3];
    const float* Wp = (const float*)d_in[4];
    float* out = (float*)d_out;

    // workspace: Q,K,Vt bf16 2MB each + pacc bf16 16.8MB + pl 0.5MB = 23.3MB
    ushort* Q    = (ushort*)d_ws;
    ushort* K    = Q  + (size_t)B * N * C;
    ushort* Vt   = K  + (size_t)B * N * C;
    ushort* pacc = Vt + (size_t)B * N * C;
    float*  pl   = (float*)(pacc + (size_t)NQW * KVSPLIT * 32 * 64);

    qkv_kernel<<<B * 256, 256, 0, stream>>>(x, Wq, Wk, Wv, Q, K, Vt);
    attn_kernel<<<128 * KVSPLIT, 256, 0, stream>>>(Q, K, Vt, pacc, pl);
    proj_kernel<<<NQW, 256, 0, stream>>>(x, Wp, pacc, pl, out);
}

// Round 9
// 58.888 us; speedup vs baseline: 1.6563x; 1.6563x over previous
//
#include <hip/hip_runtime.h>
#include <hip/hip_bf16.h>

typedef __attribute__((ext_vector_type(4))) float f32x4;
typedef __attribute__((ext_vector_type(8))) short bf16x8;

constexpr int B = 4, C = 64, N = 4096;
constexpr int KVSPLIT = 8;
constexpr int CHUNK = N / KVSPLIT;   // 512
constexpr int NQT = B * N / 16;      // 1024 q-tiles of 16 rows

__device__ __forceinline__ float bf2f(ushort u) {
    union { float f; unsigned int u32; } x;
    x.u32 = ((unsigned int)u) << 16;
    return x.f;
}
__device__ __forceinline__ ushort f2bf(float f) {
    union { float f; unsigned int u; } x;
    x.f = f;
    unsigned int r = x.u + 0x7FFFu + ((x.u >> 16) & 1u);
    return (ushort)(r >> 16);
}
// guaranteed-order pair: lo 16 = a (even index), hi 16 = b (odd index)
__device__ __forceinline__ uint packbf2(float a, float b) {
    return (uint)f2bf(a) | ((uint)f2bf(b) << 16);
}
__device__ __forceinline__ bf16x8 pack8(uint a, uint b, uint c, uint d) {
    union { uint u[4]; bf16x8 v; } x;
    x.u[0] = a; x.u[1] = b; x.u[2] = c; x.u[3] = d;
    return x.v;
}

#define MFMA16(a, b, c) __builtin_amdgcn_mfma_f32_16x16x32_bf16(a, b, c, 0, 0, 0)

// ---------------------------------------------------------------------------
// Kernel 1: QKV via MFMA (R6-PASSED, unchanged). Zero LDS, zero barriers.
// ---------------------------------------------------------------------------
__global__ __launch_bounds__(256) void qkv_kernel(
    const float* __restrict__ x, const float* __restrict__ Wq,
    const float* __restrict__ Wk, const float* __restrict__ Wv,
    ushort* __restrict__ Q, ushort* __restrict__ K, ushort* __restrict__ Vt)
{
    const int b  = blockIdx.x >> 8;
    const int n0 = (blockIdx.x & 255) << 4;
    const int lane = threadIdx.x & 63;
    const int w  = threadIdx.x >> 6;
    const int lq = lane & 15, lg = lane >> 4;

    bf16x8 bfrag[2];
#pragma unroll
    for (int kk = 0; kk < 2; ++kk) {
        float xv[8];
#pragma unroll
        for (int j = 0; j < 8; ++j)
            xv[j] = x[(size_t)(b * C + kk * 32 + lg * 8 + j) * N + n0 + lq];
        bfrag[kk] = pack8(packbf2(xv[0], xv[1]), packbf2(xv[2], xv[3]),
                          packbf2(xv[4], xv[5]), packbf2(xv[6], xv[7]));
    }

    const float* Ws[3] = {Wq, Wk, Wv};
#pragma unroll
    for (int m = 0; m < 3; ++m) {
        const float scale = (m == 0) ? 0.125f : 1.0f;
        f32x4 acc = {0.f, 0.f, 0.f, 0.f};
#pragma unroll
        for (int kk = 0; kk < 2; ++kk) {
            const float* wp = Ws[m] + (size_t)(w * 16 + lq) * C + kk * 32 + lg * 8;
            const float4 w0 = *(const float4*)wp;
            const float4 w1 = *(const float4*)(wp + 4);
            const bf16x8 af = pack8(
                packbf2(w0.x * scale, w0.y * scale), packbf2(w0.z * scale, w0.w * scale),
                packbf2(w1.x * scale, w1.y * scale), packbf2(w1.z * scale, w1.w * scale));
            acc = MFMA16(af, bfrag[kk], acc);
        }
        if (m < 2) {   // Q/K [b][n][c]
            uint2 u;
            u.x = packbf2(acc[0], acc[1]);
            u.y = packbf2(acc[2], acc[3]);
            ushort* dst = (m == 0 ? Q : K) + ((size_t)(b * N + n0 + lq)) * C + w * 16 + 4 * lg;
            *(uint2*)dst = u;
        } else {       // Vt [b][c][n]
#pragma unroll
            for (int j = 0; j < 4; ++j)
                Vt[(size_t)(b * C + w * 16 + 4 * lg + j) * N + n0 + lq] = f2bf(acc[j]);
        }
    }
}

// ---------------------------------------------------------------------------
// Kernel 2: split-KV attention — R6-PASSED KERNEL, only KVSPLIT 4->8:
// grid 2048 (8 blocks/CU of work, 7 resident via 22.5KB LDS), per-block
// NT 32->16. s=blk&7 -> one (b,s) chunk-set per XCD L2. Epilogue: bf16 pacc
// + fp32 pl partial stores (NO atomics — R7 showed cross-XCD atomic cost).
// ---------------------------------------------------------------------------
__global__ __launch_bounds__(256, 7) void attn_kernel(
    const ushort* __restrict__ Q, const ushort* __restrict__ K,
    const ushort* __restrict__ Vt, ushort* __restrict__ pacc,
    float* __restrict__ pl)
{
    __shared__ ushort Ks[2][32][68];                              // 136B rows
    __shared__ ushort Vs[2][64][36];                              // 72B rows
    __shared__ ushort p_lds[4][16][36] __attribute__((aligned(16)));

    const int tid  = threadIdx.x;
    const int wave = tid >> 6, lane = tid & 63;
    const int lq = lane & 15, lg = lane >> 4;
    const int qg = blockIdx.x >> 3, s = blockIdx.x & 7;   // split <-> XCD
    const int qtg = qg * 4 + wave;          // global q-tile id, 0..1023
    const int b   = qtg >> 8;
    const int q0  = (qtg & 255) << 4;

    const ushort* Qb = Q  + ((size_t)b * N + q0) * C;
    const ushort* Kb = K  + (size_t)b * N * C + (size_t)s * CHUNK * C;
    const ushort* Vb = Vt + (size_t)b * C * N + (size_t)s * CHUNK;

    const int krow = tid >> 3, kseg = tid & 7;
    const int vrow = tid >> 2, vseg = tid & 3;
    const ushort* kgp = Kb + (size_t)krow * C + kseg * 8;
    const ushort* vgp = Vb + (size_t)vrow * N + vseg * 8;

    const bf16x8 qf0 = *(const bf16x8*)(Qb + (size_t)lq * C + lg * 8);
    const bf16x8 qf1 = *(const bf16x8*)(Qb + (size_t)lq * C + 32 + lg * 8);

    f32x4 acc[4];
#pragma unroll
    for (int nt = 0; nt < 4; ++nt) acc[nt] = (f32x4){0.f, 0.f, 0.f, 0.f};
    float psum[4] = {0.f, 0.f, 0.f, 0.f};

    {   // prologue: stage tile 0
        bf16x8 kv = *(const bf16x8*)kgp;
        bf16x8 vv = *(const bf16x8*)vgp;
        *(bf16x8*)&Ks[0][krow][kseg * 8] = kv;
        *(bf16x8*)&Vs[0][vrow][vseg * 8] = vv;
    }
    __syncthreads();

    constexpr int NT = CHUNK / 32;   // 16 tiles
    for (int t = 0; t < NT; ++t) {
        const int cur = t & 1;
        bf16x8 knx, vnx;
        if (t + 1 < NT) {   // T14: issue next tile's loads early
            knx = *(const bf16x8*)(kgp + (size_t)(t + 1) * 32 * C);
            vnx = *(const bf16x8*)(vgp + (t + 1) * 32);
        }

        const bf16x8 k00 = *(const bf16x8*)&Ks[cur][lq][lg * 8];
        const bf16x8 k01 = *(const bf16x8*)&Ks[cur][lq][32 + lg * 8];
        const bf16x8 k10 = *(const bf16x8*)&Ks[cur][16 + lq][lg * 8];
        const bf16x8 k11 = *(const bf16x8*)&Ks[cur][16 + lq][32 + lg * 8];

        f32x4 s0 = (f32x4){0.f, 0.f, 0.f, 0.f};
        f32x4 s1 = (f32x4){0.f, 0.f, 0.f, 0.f};
        s0 = MFMA16(qf0, k00, s0);
        s0 = MFMA16(qf1, k01, s0);
        s1 = MFMA16(qf0, k10, s1);
        s1 = MFMA16(qf1, k11, s1);

        float p0v[4], p1v[4];
#pragma unroll
        for (int j = 0; j < 4; ++j) {
            p0v[j] = __expf(fminf(s0[j], 30.f));
            p1v[j] = __expf(fminf(s1[j], 30.f));
            psum[j] += p0v[j] + p1v[j];     // deferred denominator
        }
#pragma unroll
        for (int j = 0; j < 4; ++j) {
            const int row = lg * 4 + j;
            p_lds[wave][row][lq]      = f2bf(p0v[j]);
            p_lds[wave][row][lq + 16] = f2bf(p1v[j]);
        }
        const bf16x8 pa = *(const bf16x8*)&p_lds[wave][lq][lg * 8];
#pragma unroll
        for (int nt = 0; nt < 4; ++nt) {
            const bf16x8 vf = *(const bf16x8*)&Vs[cur][nt * 16 + lq][lg * 8];
            acc[nt] = MFMA16(pa, vf, acc[nt]);
        }

        if (t + 1 < NT) {
            *(bf16x8*)&Ks[cur ^ 1][krow][kseg * 8] = knx;
            *(bf16x8*)&Vs[cur ^ 1][vrow][vseg * 8] = vnx;
        }
        __syncthreads();
    }

#pragma unroll
    for (int off = 1; off < 16; off <<= 1) {
#pragma unroll
        for (int j = 0; j < 4; ++j) psum[j] += __shfl_xor(psum[j], off);
    }

    ushort* pa_out = pacc + (size_t)(qtg * KVSPLIT + s) * (16 * 64);
#pragma unroll
    for (int nt = 0; nt < 4; ++nt)
#pragma unroll
        for (int j = 0; j < 4; ++j)
            pa_out[(lg * 4 + j) * 64 + nt * 16 + lq] = f2bf(acc[nt][j]);
    if (lq == 0) {
#pragma unroll
        for (int j = 0; j < 4; ++j)
            pl[(size_t)(qtg * KVSPLIT + s) * 16 + lg * 4 + j] = psum[j];
    }
}

// ---------------------------------------------------------------------------
// Kernel 3: combine 8 splits + projection via MFMA + residual (R6-passed
// structure, split loop extended to 8). grid = B*128 (32 tokens/blk).
// ---------------------------------------------------------------------------
__global__ __launch_bounds__(256) void proj_kernel(
    const float* __restrict__ x, const float* __restrict__ Wp,
    const ushort* __restrict__ pacc, const float* __restrict__ pl,
    float* __restrict__ out)
{
    __shared__ __attribute__((aligned(16))) ushort Hs[32][68];
    __shared__ float linv_s[32];
    const int tid = threadIdx.x;
    const int b   = blockIdx.x >> 7;
    const int n0  = (blockIdx.x & 127) << 5;
    const int qt0 = b * 256 + (n0 >> 4);     // first of 2 q-tiles (16 rows each)

    if (tid < 32) {
        const int qq = tid >> 4, row = tid & 15;
        float sm = 0.f;
#pragma unroll
        for (int s2 = 0; s2 < KVSPLIT; ++s2)
            sm += pl[(size_t)((qt0 + qq) * KVSPLIT + s2) * 16 + row];
        linv_s[tid] = 1.f / sm;
    }
    {   // combine 8 splits: thread -> (tok, 8-channel segment)
        const int tok = tid >> 3, c8 = (tid & 7) * 8;
        const ushort* base = pacc
            + ((size_t)(qt0 + (tok >> 4)) * KVSPLIT) * 1024 + (tok & 15) * 64 + c8;
        float sm[8] = {0.f, 0.f, 0.f, 0.f, 0.f, 0.f, 0.f, 0.f};
#pragma unroll
        for (int s2 = 0; s2 < KVSPLIT; ++s2) {
            union { bf16x8 v; ushort u[8]; } pk;
            pk.v = *(const bf16x8*)(base + s2 * 1024);
#pragma unroll
            for (int j = 0; j < 8; ++j) sm[j] += bf2f(pk.u[j]);
        }
        *(bf16x8*)&Hs[tok][c8] = pack8(
            packbf2(sm[0], sm[1]), packbf2(sm[2], sm[3]),
            packbf2(sm[4], sm[5]), packbf2(sm[6], sm[7]));
    }
    __syncthreads();

    const int lane = tid & 63, w = tid >> 6;
    const int lq = lane & 15, lg = lane >> 4;

    bf16x8 af[2];
#pragma unroll
    for (int kk = 0; kk < 2; ++kk) {
        const float* wp = Wp + (size_t)(w * 16 + lq) * C + kk * 32 + lg * 8;
        const float4 w0 = *(const float4*)wp;
        const float4 w1 = *(const float4*)(wp + 4);
        af[kk] = pack8(packbf2(w0.x, w0.y), packbf2(w0.z, w0.w),
                       packbf2(w1.x, w1.y), packbf2(w1.z, w1.w));
    }

#pragma unroll
    for (int th = 0; th < 2; ++th) {          // two 16-token D tiles
        f32x4 acc = {0.f, 0.f, 0.f, 0.f};
#pragma unroll
        for (int kk = 0; kk < 2; ++kk) {
            const bf16x8 bf = *(const bf16x8*)&Hs[th * 16 + lq][kk * 32 + lg * 8];
            acc = MFMA16(af[kk], bf, acc);
        }
        const float li = linv_s[th * 16 + lq];
#pragma unroll
        for (int j = 0; j < 4; ++j) {
            const int o = w * 16 + 4 * lg + j;
            const size_t idx = (size_t)(b * C + o) * N + n0 + th * 16 + lq;
            out[idx] = x[idx] + acc[j] * li;
        }
    }
}

// ---------------------------------------------------------------------------
extern "C" void kernel_launch(void* const* d_in, const int* in_sizes, int n_in,
                              void* d_out, int out_size, void* d_ws, size_t ws_size,
                              hipStream_t stream)
{
    const float* x  = (const float*)d_in[0];
    const float* Wq = (const float*)d_in[1];
    const float* Wk = (const float*)d_in[2];
    const float* Wv = (const float*)d_in[3];
    const float* Wp = (const float*)d_in[4];
    float* out = (float*)d_out;

    // workspace: Q,K,Vt bf16 2MB each + pacc bf16 16.8MB + pl 0.5MB = 23.3MB
    ushort* Q    = (ushort*)d_ws;
    ushort* K    = Q  + (size_t)B * N * C;
    ushort* Vt   = K  + (size_t)B * N * C;
    ushort* pacc = Vt + (size_t)B * N * C;
    float*  pl   = (float*)(pacc + (size_t)NQT * KVSPLIT * 16 * 64);

    qkv_kernel<<<B * 256, 256, 0, stream>>>(x, Wq, Wk, Wv, Q, K, Vt);
    attn_kernel<<<256 * KVSPLIT, 256, 0, stream>>>(Q, K, Vt, pacc, pl);
    proj_kernel<<<B * 128, 256, 0, stream>>>(x, Wp, pacc, pl, out);
}

// Round 10
// 52.612 us; speedup vs baseline: 1.8538x; 1.1193x over previous
//
#include <hip/hip_runtime.h>
#include <hip/hip_bf16.h>

typedef __attribute__((ext_vector_type(4))) float f32x4;
typedef __attribute__((ext_vector_type(8))) short bf16x8;

constexpr int B = 4, C = 64, N = 4096;
constexpr int KVSPLIT = 8;
constexpr int CHUNK = N / KVSPLIT;   // 512
constexpr int NQT = B * N / 16;      // 1024 q-tiles of 16 rows

__device__ __forceinline__ float bf2f(ushort u) {
    union { float f; unsigned int u32; } x;
    x.u32 = ((unsigned int)u) << 16;
    return x.f;
}
__device__ __forceinline__ ushort f2bf(float f) {
    union { float f; unsigned int u; } x;
    x.f = f;
    unsigned int r = x.u + 0x7FFFu + ((x.u >> 16) & 1u);
    return (ushort)(r >> 16);
}
// native packed convert: lo 16 = a, hi 16 = b (v_cvt_pk_bf16_f32 via compiler)
__device__ __forceinline__ uint packbf2(float a, float b) {
    union { __hip_bfloat162 h; uint u; } x;
    x.h = __float22bfloat162_rn(float2{a, b});
    return x.u;
}
__device__ __forceinline__ bf16x8 pack8(uint a, uint b, uint c, uint d) {
    union { uint u[4]; bf16x8 v; } x;
    x.u[0] = a; x.u[1] = b; x.u[2] = c; x.u[3] = d;
    return x.v;
}

#define MFMA16(a, b, c) __builtin_amdgcn_mfma_f32_16x16x32_bf16(a, b, c, 0, 0, 0)

// ---------------------------------------------------------------------------
// Kernel 1: QKV via MFMA (R6/R9-PASSED structure; native packed converts).
// ---------------------------------------------------------------------------
__global__ __launch_bounds__(256) void qkv_kernel(
    const float* __restrict__ x, const float* __restrict__ Wq,
    const float* __restrict__ Wk, const float* __restrict__ Wv,
    ushort* __restrict__ Q, ushort* __restrict__ K, ushort* __restrict__ Vt)
{
    const int b  = blockIdx.x >> 8;
    const int n0 = (blockIdx.x & 255) << 4;
    const int lane = threadIdx.x & 63;
    const int w  = threadIdx.x >> 6;
    const int lq = lane & 15, lg = lane >> 4;

    bf16x8 bfrag[2];
#pragma unroll
    for (int kk = 0; kk < 2; ++kk) {
        float xv[8];
#pragma unroll
        for (int j = 0; j < 8; ++j)
            xv[j] = x[(size_t)(b * C + kk * 32 + lg * 8 + j) * N + n0 + lq];
        bfrag[kk] = pack8(packbf2(xv[0], xv[1]), packbf2(xv[2], xv[3]),
                          packbf2(xv[4], xv[5]), packbf2(xv[6], xv[7]));
    }

    const float* Ws[3] = {Wq, Wk, Wv};
#pragma unroll
    for (int m = 0; m < 3; ++m) {
        const float scale = (m == 0) ? 0.125f : 1.0f;
        f32x4 acc = {0.f, 0.f, 0.f, 0.f};
#pragma unroll
        for (int kk = 0; kk < 2; ++kk) {
            const float* wp = Ws[m] + (size_t)(w * 16 + lq) * C + kk * 32 + lg * 8;
            const float4 w0 = *(const float4*)wp;
            const float4 w1 = *(const float4*)(wp + 4);
            const bf16x8 af = pack8(
                packbf2(w0.x * scale, w0.y * scale), packbf2(w0.z * scale, w0.w * scale),
                packbf2(w1.x * scale, w1.y * scale), packbf2(w1.z * scale, w1.w * scale));
            acc = MFMA16(af, bfrag[kk], acc);
        }
        if (m < 2) {   // Q/K [b][n][c]
            uint2 u;
            u.x = packbf2(acc[0], acc[1]);
            u.y = packbf2(acc[2], acc[3]);
            ushort* dst = (m == 0 ? Q : K) + ((size_t)(b * N + n0 + lq)) * C + w * 16 + 4 * lg;
            *(uint2*)dst = u;
        } else {       // Vt [b][c][n]
#pragma unroll
            for (int j = 0; j < 4; ++j)
                Vt[(size_t)(b * C + w * 16 + 4 * lg + j) * N + n0 + lq] = f2bf(acc[j]);
        }
    }
}

// ---------------------------------------------------------------------------
// Kernel 2: split-KV attention. R6/R9-verified layouts/staging; each wave now
// owns 2 q-tiles (32 rows) so K/V fragment reads feed 16 MFMAs instead of 8
// (per-CU LDS read traffic halves). Block = 128 q-rows; grid = 128 x 8 splits
// = 1024 = exactly 4 blocks/CU, no tail. p_lds reused per qi (wave-private,
// same-wave DS order). Native packed bf16 converts in the P-pack path.
// ---------------------------------------------------------------------------
__global__ __launch_bounds__(256, 4) void attn_kernel(
    const ushort* __restrict__ Q, const ushort* __restrict__ K,
    const ushort* __restrict__ Vt, ushort* __restrict__ pacc,
    float* __restrict__ pl)
{
    __shared__ ushort Ks[2][32][68];                              // 136B rows
    __shared__ ushort Vs[2][64][36];                              // 72B rows
    __shared__ ushort p_lds[4][16][36] __attribute__((aligned(16)));

    const int tid  = threadIdx.x;
    const int wave = tid >> 6, lane = tid & 63;
    const int lq = lane & 15, lg = lane >> 4;
    const int qb = blockIdx.x >> 3, s = blockIdx.x & 7;   // split <-> XCD
    const int b  = qb >> 5;
    const int q0 = (qb & 31) * 128 + wave * 32;           // wave's 32 rows
    const int gqt0 = b * 256 + (qb & 31) * 8 + wave * 2;  // q-tile id of qi=0

    const ushort* Qb = Q  + ((size_t)b * N + q0) * C;
    const ushort* Kb = K  + (size_t)b * N * C + (size_t)s * CHUNK * C;
    const ushort* Vb = Vt + (size_t)b * C * N + (size_t)s * CHUNK;

    const int krow = tid >> 3, kseg = tid & 7;
    const int vrow = tid >> 2, vseg = tid & 3;
    const ushort* kgp = Kb + (size_t)krow * C + kseg * 8;
    const ushort* vgp = Vb + (size_t)vrow * N + vseg * 8;

    bf16x8 qf[2][2];
#pragma unroll
    for (int qi = 0; qi < 2; ++qi) {
        qf[qi][0] = *(const bf16x8*)(Qb + (size_t)(qi * 16 + lq) * C + lg * 8);
        qf[qi][1] = *(const bf16x8*)(Qb + (size_t)(qi * 16 + lq) * C + 32 + lg * 8);
    }

    f32x4 acc[2][4];
#pragma unroll
    for (int qi = 0; qi < 2; ++qi)
#pragma unroll
        for (int nt = 0; nt < 4; ++nt) acc[qi][nt] = (f32x4){0.f, 0.f, 0.f, 0.f};
    float psum[2][4] = {{0.f, 0.f, 0.f, 0.f}, {0.f, 0.f, 0.f, 0.f}};

    {   // prologue: stage tile 0
        bf16x8 kv = *(const bf16x8*)kgp;
        bf16x8 vv = *(const bf16x8*)vgp;
        *(bf16x8*)&Ks[0][krow][kseg * 8] = kv;
        *(bf16x8*)&Vs[0][vrow][vseg * 8] = vv;
    }
    __syncthreads();

    constexpr int NT = CHUNK / 32;   // 16 tiles
    for (int t = 0; t < NT; ++t) {
        const int cur = t & 1;
        bf16x8 knx, vnx;
        if (t + 1 < NT) {   // T14: issue next tile's loads early
            knx = *(const bf16x8*)(kgp + (size_t)(t + 1) * 32 * C);
            vnx = *(const bf16x8*)(vgp + (t + 1) * 32);
        }

        // shared fragment reads: once per tile, used by BOTH q-tiles
        const bf16x8 k00 = *(const bf16x8*)&Ks[cur][lq][lg * 8];
        const bf16x8 k01 = *(const bf16x8*)&Ks[cur][lq][32 + lg * 8];
        const bf16x8 k10 = *(const bf16x8*)&Ks[cur][16 + lq][lg * 8];
        const bf16x8 k11 = *(const bf16x8*)&Ks[cur][16 + lq][32 + lg * 8];
        bf16x8 vf[4];
#pragma unroll
        for (int nt = 0; nt < 4; ++nt)
            vf[nt] = *(const bf16x8*)&Vs[cur][nt * 16 + lq][lg * 8];

#pragma unroll
        for (int qi = 0; qi < 2; ++qi) {
            f32x4 s0 = (f32x4){0.f, 0.f, 0.f, 0.f};
            f32x4 s1 = (f32x4){0.f, 0.f, 0.f, 0.f};
            s0 = MFMA16(qf[qi][0], k00, s0);
            s0 = MFMA16(qf[qi][1], k01, s0);
            s1 = MFMA16(qf[qi][0], k10, s1);
            s1 = MFMA16(qf[qi][1], k11, s1);

            float p0v[4], p1v[4];
#pragma unroll
            for (int j = 0; j < 4; ++j) {
                p0v[j] = __expf(fminf(s0[j], 30.f));
                p1v[j] = __expf(fminf(s1[j], 30.f));
                psum[qi][j] += p0v[j] + p1v[j];
            }
            // packed p_lds write: row (lg*4+j), cols [lq] and [lq+16]
#pragma unroll
            for (int j = 0; j < 4; ++j) {
                const int row = lg * 4 + j;
                p_lds[wave][row][lq]      = f2bf(p0v[j]);
                p_lds[wave][row][lq + 16] = f2bf(p1v[j]);
            }
            const bf16x8 pa = *(const bf16x8*)&p_lds[wave][lq][lg * 8];
#pragma unroll
            for (int nt = 0; nt < 4; ++nt)
                acc[qi][nt] = MFMA16(pa, vf[nt], acc[qi][nt]);
        }

        if (t + 1 < NT) {
            *(bf16x8*)&Ks[cur ^ 1][krow][kseg * 8] = knx;
            *(bf16x8*)&Vs[cur ^ 1][vrow][vseg * 8] = vnx;
        }
        __syncthreads();
    }

#pragma unroll
    for (int off = 1; off < 16; off <<= 1) {
#pragma unroll
        for (int qi = 0; qi < 2; ++qi)
#pragma unroll
            for (int j = 0; j < 4; ++j)
                psum[qi][j] += __shfl_xor(psum[qi][j], off);
    }

#pragma unroll
    for (int qi = 0; qi < 2; ++qi) {
        ushort* pa_out = pacc + (size_t)((gqt0 + qi) * KVSPLIT + s) * (16 * 64);
#pragma unroll
        for (int nt = 0; nt < 4; ++nt)
#pragma unroll
            for (int j = 0; j < 4; ++j)
                pa_out[(lg * 4 + j) * 64 + nt * 16 + lq] = f2bf(acc[qi][nt][j]);
        if (lq == 0) {
#pragma unroll
            for (int j = 0; j < 4; ++j)
                pl[(size_t)((gqt0 + qi) * KVSPLIT + s) * 16 + lg * 4 + j] = psum[qi][j];
        }
    }
}

// ---------------------------------------------------------------------------
// Kernel 3: combine 8 splits + projection via MFMA + residual (R9-PASSED,
// unchanged; native packed converts). grid = B*128 (32 tokens/blk).
// ---------------------------------------------------------------------------
__global__ __launch_bounds__(256) void proj_kernel(
    const float* __restrict__ x, const float* __restrict__ Wp,
    const ushort* __restrict__ pacc, const float* __restrict__ pl,
    float* __restrict__ out)
{
    __shared__ __attribute__((aligned(16))) ushort Hs[32][68];
    __shared__ float linv_s[32];
    const int tid = threadIdx.x;
    const int b   = blockIdx.x >> 7;
    const int n0  = (blockIdx.x & 127) << 5;
    const int qt0 = b * 256 + (n0 >> 4);     // first of 2 q-tiles (16 rows each)

    if (tid < 32) {
        const int qq = tid >> 4, row = tid & 15;
        float sm = 0.f;
#pragma unroll
        for (int s2 = 0; s2 < KVSPLIT; ++s2)
            sm += pl[(size_t)((qt0 + qq) * KVSPLIT + s2) * 16 + row];
        linv_s[tid] = 1.f / sm;
    }
    {   // combine 8 splits: thread -> (tok, 8-channel segment)
        const int tok = tid >> 3, c8 = (tid & 7) * 8;
        const ushort* base = pacc
            + ((size_t)(qt0 + (tok >> 4)) * KVSPLIT) * 1024 + (tok & 15) * 64 + c8;
        float sm[8] = {0.f, 0.f, 0.f, 0.f, 0.f, 0.f, 0.f, 0.f};
#pragma unroll
        for (int s2 = 0; s2 < KVSPLIT; ++s2) {
            union { bf16x8 v; ushort u[8]; } pk;
            pk.v = *(const bf16x8*)(base + s2 * 1024);
#pragma unroll
            for (int j = 0; j < 8; ++j) sm[j] += bf2f(pk.u[j]);
        }
        *(bf16x8*)&Hs[tok][c8] = pack8(
            packbf2(sm[0], sm[1]), packbf2(sm[2], sm[3]),
            packbf2(sm[4], sm[5]), packbf2(sm[6], sm[7]));
    }
    __syncthreads();

    const int lane = tid & 63, w = tid >> 6;
    const int lq = lane & 15, lg = lane >> 4;

    bf16x8 af[2];
#pragma unroll
    for (int kk = 0; kk < 2; ++kk) {
        const float* wp = Wp + (size_t)(w * 16 + lq) * C + kk * 32 + lg * 8;
        const float4 w0 = *(const float4*)wp;
        const float4 w1 = *(const float4*)(wp + 4);
        af[kk] = pack8(packbf2(w0.x, w0.y), packbf2(w0.z, w0.w),
                       packbf2(w1.x, w1.y), packbf2(w1.z, w1.w));
    }

#pragma unroll
    for (int th = 0; th < 2; ++th) {          // two 16-token D tiles
        f32x4 acc = {0.f, 0.f, 0.f, 0.f};
#pragma unroll
        for (int kk = 0; kk < 2; ++kk) {
            const bf16x8 bf = *(const bf16x8*)&Hs[th * 16 + lq][kk * 32 + lg * 8];
            acc = MFMA16(af[kk], bf, acc);
        }
        const float li = linv_s[th * 16 + lq];
#pragma unroll
        for (int j = 0; j < 4; ++j) {
            const int o = w * 16 + 4 * lg + j;
            const size_t idx = (size_t)(b * C + o) * N + n0 + th * 16 + lq;
            out[idx] = x[idx] + acc[j] * li;
        }
    }
}

// ---------------------------------------------------------------------------
extern "C" void kernel_launch(void* const* d_in, const int* in_sizes, int n_in,
                              void* d_out, int out_size, void* d_ws, size_t ws_size,
                              hipStream_t stream)
{
    const float* x  = (const float*)d_in[0];
    const float* Wq = (const float*)d_in[1];
    const float* Wk = (const float*)d_in[2];
    const float* Wv = (const float*)d_in[3];
    const float* Wp = (const float*)d_in[4];
    float* out = (float*)d_out;

    // workspace: Q,K,Vt bf16 2MB each + pacc bf16 16.8MB + pl 0.5MB = 23.3MB
    ushort* Q    = (ushort*)d_ws;
    ushort* K    = Q  + (size_t)B * N * C;
    ushort* Vt   = K  + (size_t)B * N * C;
    ushort* pacc = Vt + (size_t)B * N * C;
    float*  pl   = (float*)(pacc + (size_t)NQT * KVSPLIT * 16 * 64);

    qkv_kernel<<<B * 256, 256, 0, stream>>>(x, Wq, Wk, Wv, Q, K, Vt);
    attn_kernel<<<128 * KVSPLIT, 256, 0, stream>>>(Q, K, Vt, pacc, pl);
    proj_kernel<<<B * 128, 256, 0, stream>>>(x, Wp, pacc, pl, out);
}